// Round 2
// baseline (1335.619 us; speedup 1.0000x reference)
//
#include <hip/hip_runtime.h>
#include <cmath>

// ---------------------------------------------------------------------------
// CapsNet forward. Round 3 (resubmit — prior rounds failed on GPU acquisition):
//  - prim_mfma: BK=64, 16B staging, XOR-swizzled unpadded LDS (64KB), K-split 12.
//  - dec3: 256x64 tile, w3 read exactly once, A = pre-converted bf16 h2.
//  - dec2: epilogue writes bf16 h2 directly (identical rounding to old dec3 cvt).
// ---------------------------------------------------------------------------

constexpr int BATCH = 256;

enum { AM_PLAIN = 0, AM_CONV1 = 1 };
enum { EPI_NONE = 0, EPI_RELU = 1, EPI_SIG = 2, EPI_RELU_SPLIT = 3, EPI_RELU_H2B = 4 };

typedef short bf16x8 __attribute__((ext_vector_type(8)));
typedef unsigned short us8 __attribute__((ext_vector_type(8)));
typedef float f32x4 __attribute__((ext_vector_type(4)));

__device__ __forceinline__ unsigned short f2b(float v) {
  unsigned int u = __float_as_uint(v);
  u += 0x7FFFu + ((u >> 16) & 1u);
  return (unsigned short)(u >> 16);
}
__device__ __forceinline__ void split_bf(float v, unsigned short& h, unsigned short& l) {
  h = f2b(v);
  l = f2b(v - __uint_as_float(((unsigned int)h) << 16));
}

// ---------------------------------------------------------------------------
// fp32 tiled GEMM (conv1 and dec2): C[M,N] = A[M,K] * B[N,K]^T
// ---------------------------------------------------------------------------
template <int BM, int BN, int TM, int TN, int AMODE, int EPI>
__global__ __launch_bounds__(256, 2) void gemm_k(
    const float* __restrict__ A, const float* __restrict__ Bm,
    const float* __restrict__ bias, float* __restrict__ C,
    int M, int N, int K, int k_len,
    unsigned short* __restrict__ Chi, unsigned short* __restrict__ Clo) {
  static_assert(TM == 8 && TN == 8, "microtile fixed at 8x8");
  constexpr int BK = 8;
  constexpr int TX = BN / TN;

  const int tid = threadIdx.x;
  const int tx = tid % TX;
  const int ty = tid / TX;
  const int n0 = blockIdx.x * BN;
  const int m0 = blockIdx.y * BM;
  const int k_begin = blockIdx.z * k_len;
  const int k_end = k_begin + k_len;
  C += (size_t)blockIdx.z * (size_t)M * (size_t)N;

  __shared__ float As[BK][BM + 4];
  __shared__ float Bs[BK][BN + 4];

  float acc[TM][TN] = {};

  for (int kt = k_begin; kt < k_end; kt += BK) {
    __syncthreads();
    for (int base = tid * 4; base < BM * BK; base += 1024) {
      int ml = base / BK;
      int kl = base % BK;
#pragma unroll
      for (int j = 0; j < 4; j++) {
        int k = kt + kl + j;
        float v = 0.f;
        if (k < k_end) {
          if constexpr (AMODE == AM_PLAIN) {
            v = A[(size_t)(m0 + ml) * K + k];
          } else {
            int m = m0 + ml;
            int b = m / 144, p = m - b * 144;
            int py = p / 12, px = p - py * 12;
            int ky = k / 9, kx = k - ky * 9;
            v = A[b * 400 + (py + ky) * 20 + (px + kx)];
          }
        }
        As[kl + j][ml] = v;
      }
    }
    for (int base = tid * 4; base < BN * BK; base += 1024) {
      int nl = base / BK;
      int kl = base % BK;
#pragma unroll
      for (int j = 0; j < 4; j++) {
        int k = kt + kl + j;
        float v = 0.f;
        if (k < k_end) v = Bm[(size_t)(n0 + nl) * K + k];
        Bs[kl + j][nl] = v;
      }
    }
    __syncthreads();
#pragma unroll
    for (int kk = 0; kk < BK; kk++) {
      float af[TM], bf[TN];
      const float4* ap = reinterpret_cast<const float4*>(&As[kk][ty * TM]);
      reinterpret_cast<float4*>(af)[0] = ap[0];
      reinterpret_cast<float4*>(af)[1] = ap[1];
      const float4* bp = reinterpret_cast<const float4*>(&Bs[kk][tx * TN]);
      reinterpret_cast<float4*>(bf)[0] = bp[0];
      reinterpret_cast<float4*>(bf)[1] = bp[1];
#pragma unroll
      for (int i = 0; i < TM; i++)
#pragma unroll
        for (int j = 0; j < TN; j++) acc[i][j] += af[i] * bf[j];
    }
  }

#pragma unroll
  for (int i = 0; i < TM; i++) {
    int m = m0 + ty * TM + i;
#pragma unroll
    for (int j = 0; j < TN; j++) {
      int n = n0 + tx * TN + j;
      float v = acc[i][j];
      if constexpr (EPI == EPI_RELU) {
        v += bias[n];
        v = fmaxf(v, 0.f);
        C[(size_t)m * N + n] = v;
      } else if constexpr (EPI == EPI_SIG) {
        v += bias[n];
        v = 1.f / (1.f + expf(-v));
        C[(size_t)m * N + n] = v;
      } else if constexpr (EPI == EPI_RELU_SPLIT) {
        v += bias[n];
        v = fmaxf(v, 0.f);
        unsigned short hs, ls;
        split_bf(v, hs, ls);
        Chi[(size_t)m * N + n] = hs;
        Clo[(size_t)m * N + n] = ls;
      } else if constexpr (EPI == EPI_RELU_H2B) {
        v += bias[n];
        v = fmaxf(v, 0.f);
        Chi[(size_t)m * N + n] = f2b(v);
      } else {
        C[(size_t)m * N + n] = v;
      }
    }
  }
}

// ---------------------------------------------------------------------------
// prim_w [n][cin][81] -> wT_hi/lo [n][kk*256+cin] (bf16 split)
// ---------------------------------------------------------------------------
__global__ void transpose_w_k(const float* __restrict__ w,
                              unsigned short* __restrict__ hi,
                              unsigned short* __restrict__ lo) {
  int idx = blockIdx.x * 256 + threadIdx.x;
  if (idx >= 256 * 20736) return;
  int n = idx / 20736;
  int rem = idx - n * 20736;
  int kk = rem >> 8;
  int cin = rem & 255;
  float v = w[n * 20736 + cin * 81 + kk];
  unsigned short h, l;
  split_bf(v, h, l);
  hi[idx] = h;
  lo[idx] = l;
}

// ---------------------------------------------------------------------------
// Primary-caps conv as split-bf16 MFMA implicit GEMM.
// M=4096 (b*16+q), N=256 (ch), K=20736 (kk*256+cin). K-split 12 -> partials.
// BK=64 (never crosses a 256-cin boundary since kt % 64 == 0).
// LDS: un-padded rows of 64 ushorts (128B) with chunk-XOR swizzle
//   phys_chunk = c ^ (row & 7)  applied on BOTH write and read ->
//   ds_read_b128 fragment reads are bank-conflict-free.
// C = Ahi*Bhi + Ahi*Blo + Alo*Bhi (drop lo*lo).
// ---------------------------------------------------------------------------
__global__ __launch_bounds__(256, 2) void prim_mfma_k(
    const unsigned short* __restrict__ Ahi, const unsigned short* __restrict__ Alo,
    const unsigned short* __restrict__ Bhi, const unsigned short* __restrict__ Blo,
    float* __restrict__ part) {
  __shared__ unsigned short Ah[128 * 64], Al[128 * 64];
  __shared__ unsigned short Bh[128 * 64], Bl[128 * 64];   // 64 KB total

  const int tid = threadIdx.x;
  const int wave = tid >> 6, lane = tid & 63;
  const int wm = (wave >> 1) * 64, wn = (wave & 1) * 64;
  const int cl = lane & 15, rq = lane >> 4;
  const int n0 = blockIdx.x * 128;
  const int m0 = blockIdx.y * 128;
  const int z = blockIdx.z;
  const int k_begin = z * 1728, k_end = k_begin + 1728;   // 27 tiles of 64

  f32x4 acc[4][4];
#pragma unroll
  for (int i = 0; i < 4; i++)
#pragma unroll
    for (int j = 0; j < 4; j++) acc[i][j] = f32x4{0.f, 0.f, 0.f, 0.f};

  for (int kt = k_begin; kt < k_end; kt += 64) {
    const int kk = kt >> 8;           // uniform within the tile (kt%64==0)
    const int cin0 = kt & 255;        // 0,64,128,192 -> never crosses boundary
    const int dy = kk / 9, dx = kk - dy * 9;
    __syncthreads();
#pragma unroll
    for (int j = 0; j < 4; j++) {
      int g = j * 256 + tid;          // 1024 chunks of 8 ushorts (16B)
      int row = g >> 3, c = g & 7;
      int ld = row * 64 + ((c ^ (row & 7)) << 3);
      // A: im2col of h
      int m = m0 + row;
      int b = m >> 4, q = m & 15;
      int y = q >> 2, xx = q & 3;
      size_t ga = ((size_t)(b * 144 + (y + dy) * 12 + (xx + dx)) << 8) + cin0 + c * 8;
      *(us8*)&Ah[ld] = *(const us8*)(Ahi + ga);
      *(us8*)&Al[ld] = *(const us8*)(Alo + ga);
      // B: wT rows (linear in k)
      size_t gb = (size_t)(n0 + row) * 20736 + kt + c * 8;
      *(us8*)&Bh[ld] = *(const us8*)(Bhi + gb);
      *(us8*)&Bl[ld] = *(const us8*)(Blo + gb);
    }
    __syncthreads();

#pragma unroll
    for (int ko = 0; ko < 64; ko += 32) {
      const int cb = ko >> 3;         // chunk base: 0 or 4
      bf16x8 a_hi[4], b_hi[4], t[4];
#pragma unroll
      for (int im = 0; im < 4; im++) {
        int r = wm + im * 16 + cl;    // r&7 == cl&7
        a_hi[im] = *(const bf16x8*)&Ah[r * 64 + (((cb + rq) ^ (cl & 7)) << 3)];
      }
#pragma unroll
      for (int in = 0; in < 4; in++) {
        int r = wn + in * 16 + cl;
        b_hi[in] = *(const bf16x8*)&Bh[r * 64 + (((cb + rq) ^ (cl & 7)) << 3)];
      }
#pragma unroll
      for (int im = 0; im < 4; im++)
#pragma unroll
        for (int in = 0; in < 4; in++)
          acc[im][in] = __builtin_amdgcn_mfma_f32_16x16x32_bf16(a_hi[im], b_hi[in],
                                                                acc[im][in], 0, 0, 0);
#pragma unroll
      for (int in = 0; in < 4; in++) {
        int r = wn + in * 16 + cl;
        t[in] = *(const bf16x8*)&Bl[r * 64 + (((cb + rq) ^ (cl & 7)) << 3)];
      }
#pragma unroll
      for (int im = 0; im < 4; im++)
#pragma unroll
        for (int in = 0; in < 4; in++)
          acc[im][in] = __builtin_amdgcn_mfma_f32_16x16x32_bf16(a_hi[im], t[in],
                                                                acc[im][in], 0, 0, 0);
#pragma unroll
      for (int im = 0; im < 4; im++) {
        int r = wm + im * 16 + cl;
        t[im] = *(const bf16x8*)&Al[r * 64 + (((cb + rq) ^ (cl & 7)) << 3)];
      }
#pragma unroll
      for (int im = 0; im < 4; im++)
#pragma unroll
        for (int in = 0; in < 4; in++)
          acc[im][in] = __builtin_amdgcn_mfma_f32_16x16x32_bf16(t[im], b_hi[in],
                                                                acc[im][in], 0, 0, 0);
    }
  }

  float* Cp = part + (size_t)z * 1048576;
#pragma unroll
  for (int in = 0; in < 4; in++) {
    int n = n0 + wn + in * 16 + cl;
#pragma unroll
    for (int im = 0; im < 4; im++)
#pragma unroll
      for (int r = 0; r < 4; r++) {
        int m = m0 + wm + im * 16 + rq * 4 + r;
        Cp[(size_t)m * 256 + n] = acc[im][in][r];
      }
  }
}

// ---------------------------------------------------------------------------
// Decoder layer 3: out[256,102400] = sigmoid(h2 @ w3^T + b3).
// Tile 256(M, full) x 64(N): w3 is streamed from HBM exactly ONCE.
// A comes pre-converted to bf16 (h2b from dec2's epilogue).
// Same XOR-swizzled LDS as prim_mfma. 4 waves stacked in M.
// ---------------------------------------------------------------------------
__global__ __launch_bounds__(256, 2) void dec3_mfma_k(
    const unsigned short* __restrict__ Ab,  // h2 bf16 [256][1024]
    const float* __restrict__ Bw,           // w3 [102400][1024] fp32
    const float* __restrict__ bias,
    float* __restrict__ C) {
  constexpr int K = 1024, N = 102400;
  __shared__ unsigned short As[256 * 64];   // 32 KB
  __shared__ unsigned short Bs[64 * 64];    // 8 KB

  const int tid = threadIdx.x;
  const int wave = tid >> 6, lane = tid & 63;
  const int cl = lane & 15, rq = lane >> 4;
  const int n0 = blockIdx.x * 64;

  f32x4 acc[4][4];
#pragma unroll
  for (int i = 0; i < 4; i++)
#pragma unroll
    for (int j = 0; j < 4; j++) acc[i][j] = f32x4{0.f, 0.f, 0.f, 0.f};

  for (int kt = 0; kt < K; kt += 64) {
    __syncthreads();
#pragma unroll
    for (int j = 0; j < 8; j++) {
      int g = j * 256 + tid;          // 2048 chunks: 256 rows x 8
      int row = g >> 3, c = g & 7;
      int ld = row * 64 + ((c ^ (row & 7)) << 3);
      *(us8*)&As[ld] = *(const us8*)(Ab + (size_t)row * K + kt + c * 8);
    }
#pragma unroll
    for (int j = 0; j < 2; j++) {
      int g = j * 256 + tid;          // 512 chunks: 64 rows x 8
      int row = g >> 3, c = g & 7;
      int ld = row * 64 + ((c ^ (row & 7)) << 3);
      const float* src = Bw + (size_t)(n0 + row) * K + kt + c * 8;
      float4 v0 = *(const float4*)src;
      float4 v1 = *(const float4*)(src + 4);
      us8 h;
      h[0] = f2b(v0.x); h[1] = f2b(v0.y); h[2] = f2b(v0.z); h[3] = f2b(v0.w);
      h[4] = f2b(v1.x); h[5] = f2b(v1.y); h[6] = f2b(v1.z); h[7] = f2b(v1.w);
      *(us8*)&Bs[ld] = h;
    }
    __syncthreads();
#pragma unroll
    for (int ko = 0; ko < 64; ko += 32) {
      const int cb = ko >> 3;
      bf16x8 af[4], bq[4];
#pragma unroll
      for (int im = 0; im < 4; im++) {
        int r = wave * 64 + im * 16 + cl;   // r&7 == cl&7
        af[im] = *(const bf16x8*)&As[r * 64 + (((cb + rq) ^ (cl & 7)) << 3)];
      }
#pragma unroll
      for (int in = 0; in < 4; in++) {
        int r = in * 16 + cl;
        bq[in] = *(const bf16x8*)&Bs[r * 64 + (((cb + rq) ^ (cl & 7)) << 3)];
      }
#pragma unroll
      for (int im = 0; im < 4; im++)
#pragma unroll
        for (int in = 0; in < 4; in++)
          acc[im][in] = __builtin_amdgcn_mfma_f32_16x16x32_bf16(af[im], bq[in],
                                                                acc[im][in], 0, 0, 0);
    }
  }

#pragma unroll
  for (int in = 0; in < 4; in++) {
    int n = n0 + in * 16 + cl;
    float bn = bias[n];
#pragma unroll
    for (int im = 0; im < 4; im++)
#pragma unroll
      for (int r = 0; r < 4; r++) {
        int m = wave * 64 + im * 16 + rq * 4 + r;
        float v = acc[im][in][r] + bn;
        v = 1.f / (1.f + expf(-v));
        C[(size_t)m * N + n] = v;
      }
  }
}

// ---------------------------------------------------------------------------
// Reduce K-split partials + bias, squash over 8-dim capsule, scatter to x.
// ---------------------------------------------------------------------------
__global__ void red_squash_k(const float* __restrict__ part,
                             const float* __restrict__ prim_b,
                             float* __restrict__ x) {
  const int chg = blockIdx.x;
  const int b = blockIdx.y;
  const int tid = threadIdx.x;
  const int ch_l = tid & 15;
  const int q = tid >> 4;
  const int ch = chg * 16 + ch_l;

  float val = prim_b[ch];
#pragma unroll
  for (int z = 0; z < 12; z++) val += part[z * 1048576 + (b * 16 + q) * 256 + ch];

  __shared__ float su[16][17];
  su[q][ch_l] = val;
  __syncthreads();

  const int vec = tid >> 3;
  const int i = tid & 7;
  const int ch_l2 = vec >> 1;
  const int t = vec & 1;
  float sn = 0.f;
#pragma unroll
  for (int ii = 0; ii < 8; ii++) {
    float e = su[8 * t + ii][ch_l2];
    sn += e * e;
  }
  float factor = sn / ((1.f + sn) * sqrtf(sn));
  float e = su[8 * t + i][ch_l2];
  int chh = chg * 16 + ch_l2;
  int d8 = chh >> 5, d32 = chh & 31;
  int r = d8 * 64 + d32 * 2 + t;
  x[b * 4096 + r * 8 + i] = e * factor;
}

// u_hat[b,r,co] = sum_i W[r,co,i] * x[b,r,i].  one block per r.
__global__ void uhat_k(const float* __restrict__ W, const float* __restrict__ x,
                       float* __restrict__ uhat) {
  const int r = blockIdx.x;
  const int tid = threadIdx.x;
  __shared__ float Wl[8 * 160];
  __shared__ float xl[256 * 8];
  for (int t = tid; t < 1280; t += 256) {
    int co = t >> 3, i = t & 7;
    Wl[i * 160 + co] = W[r * 1280 + t];
  }
  for (int t = tid; t < 2048; t += 256) {
    int b = t >> 3, i = t & 7;
    xl[t] = x[b * 4096 + r * 8 + i];
  }
  __syncthreads();
  for (int item = tid; item < 256 * 160; item += 256) {
    int b = item / 160;
    int co = item - b * 160;
    float acc = 0.f;
#pragma unroll
    for (int i = 0; i < 8; i++) acc += Wl[i * 160 + co] * xl[b * 8 + i];
    uhat[b * 81920 + r * 160 + co] = acc;
  }
}

__global__ void zero_b_k(float* __restrict__ bij) {
  int id = blockIdx.x * 256 + threadIdx.x;
  if (id < 5120) bij[id] = 0.f;
}

__global__ void route_iter_k(const float* __restrict__ uhat,
                             const float* __restrict__ c_rc,
                             float* __restrict__ v_out,
                             float* __restrict__ a_buf,
                             int use_uniform, int do_update) {
  const int b = blockIdx.x;
  const int tid = threadIdx.x;
  __shared__ float c_l[5120];
  __shared__ float v_l[160];
  if (!use_uniform) {
    for (int t = tid; t < 5120; t += 256) c_l[t] = c_rc[t];
  }
  __syncthreads();
  if (tid < 160) {
    const float* up = uhat + b * 81920 + tid;
    const int cls = tid >> 4;
    float acc = 0.f;
    if (use_uniform) {
#pragma unroll 8
      for (int r = 0; r < 512; r++) acc += up[r * 160];
      acc *= (1.f / 512.f);
    } else {
#pragma unroll 8
      for (int r = 0; r < 512; r++) acc += c_l[r * 10 + cls] * up[r * 160];
    }
    float sq = acc * acc;
    float vv = sq * acc / ((1.f + sq) * sqrtf(sq));
    v_l[tid] = vv;
    v_out[b * 160 + tid] = vv;
  }
  __syncthreads();
  if (do_update) {
    for (int item = tid; item < 5120; item += 256) {
      int r = item / 10;
      int c = item - r * 10;
      const float* up2 = uhat + b * 81920 + r * 160 + c * 16;
      float a = 0.f;
#pragma unroll
      for (int o = 0; o < 16; o++) a += up2[o] * v_l[c * 16 + o];
      a_buf[b * 5120 + item] = a;
    }
  }
}

__global__ void bupd_k(const float* __restrict__ a_buf, float* __restrict__ bij) {
  int id = blockIdx.x * 256 + threadIdx.x;
  if (id >= 5120) return;
  float s = 0.f;
  for (int b = 0; b < BATCH; b++) s += a_buf[b * 5120 + id];
  bij[id] += s * (1.f / 256.f);
}

__global__ void softmax_b_k(const float* __restrict__ bij, float* __restrict__ c_rc) {
  const int tid = threadIdx.x;
  __shared__ float Ml[10], Sl[10];
  if (tid < 10) {
    float m = -1e30f;
    for (int r = 0; r < 512; r++) m = fmaxf(m, bij[r * 10 + tid]);
    float s = 0.f;
    for (int r = 0; r < 512; r++) s += expf(bij[r * 10 + tid] - m);
    Ml[tid] = m;
    Sl[tid] = s;
  }
  __syncthreads();
  if (tid < 512) {
    for (int c = 0; c < 10; c++)
      c_rc[tid * 10 + c] = expf(bij[tid * 10 + c] - Ml[c]) / Sl[c];
  }
}

__global__ void classes_k(const float* __restrict__ v, float* __restrict__ sel,
                          int* __restrict__ idxb) {
  const int b = threadIdx.x;
  float cl[10], ex[10];
  for (int c = 0; c < 10; c++) {
    float s = 0.f;
    for (int o = 0; o < 16; o++) {
      float e = v[b * 160 + c * 16 + o];
      s += e * e;
    }
    cl[c] = sqrtf(s);
  }
  __shared__ float red[256];
  __shared__ float Mc[10], Sc[10];
  for (int c = 0; c < 10; c++) {
    red[b] = cl[c];
    __syncthreads();
    for (int s = 128; s > 0; s >>= 1) {
      if (b < s) red[b] = fmaxf(red[b], red[b + s]);
      __syncthreads();
    }
    if (b == 0) Mc[c] = red[0];
    __syncthreads();
  }
  for (int c = 0; c < 10; c++) {
    ex[c] = expf(cl[c] - Mc[c]);
    red[b] = ex[c];
    __syncthreads();
    for (int s = 128; s > 0; s >>= 1) {
      if (b < s) red[b] += red[b + s];
      __syncthreads();
    }
    if (b == 0) Sc[c] = red[0];
    __syncthreads();
  }
  float best = ex[0] / Sc[0];
  int bi = 0;
  for (int c = 1; c < 10; c++) {
    float p = ex[c] / Sc[c];
    if (p > best) { best = p; bi = c; }
  }
  idxb[b] = bi;
  for (int o = 0; o < 16; o++) sel[b * 16 + o] = v[b * 160 + bi * 16 + o];
}

__global__ void h1_k(const float* __restrict__ sel, const int* __restrict__ idxb,
                     const float* __restrict__ w1, const float* __restrict__ b1,
                     float* __restrict__ h1) {
  const int b = blockIdx.x;
  const int j = threadIdx.x;
  __shared__ float ssel[16];
  __shared__ int six;
  if (j < 16) ssel[j] = sel[b * 16 + j];
  if (j == 0) six = idxb[b];
  __syncthreads();
  const float* wrow = w1 + j * 160 + six * 16;
  float acc = b1[j];
#pragma unroll
  for (int o = 0; o < 16; o++) acc += ssel[o] * wrow[o];
  h1[b * 512 + j] = fmaxf(acc, 0.f);
}

// ---------------------------------------------------------------------------
// ws layout (float offsets). Peak = 35,717,120 floats = 142.9 MB.
//   [0, 20971520)           uhat  (aliases prim partials 12 x 1048576)
//   20971520: h_hi  (ushort, 4718592 floats)   } dead after prim_mfma;
//   25690112: h_lo  (ushort, 4718592 floats)   } small buffers overlay h_hi
//   30408704: wT_hi (ushort, 2654208 floats)
//   33062912: wT_lo (ushort, 2654208 floats)   -> ends 35717120
//   overlay (post-prim, inside h_hi region):
//   x @20971520  v @22020096  bij @22061056  crc @22066176  abuf @22071296
//   sel @23382016  idx @23386112  h1 @23386368  h2b(ushort) @23517440
//   dummyC @23648512
// ---------------------------------------------------------------------------
extern "C" void kernel_launch(void* const* d_in, const int* in_sizes, int n_in,
                              void* d_out, int out_size, void* d_ws, size_t ws_size,
                              hipStream_t stream) {
  const float* data    = (const float*)d_in[0];
  const float* conv1_w = (const float*)d_in[1];
  const float* conv1_b = (const float*)d_in[2];
  const float* prim_w  = (const float*)d_in[3];
  const float* prim_b  = (const float*)d_in[4];
  const float* W_digit = (const float*)d_in[5];
  const float* dec_w1  = (const float*)d_in[6];
  const float* dec_b1  = (const float*)d_in[7];
  const float* dec_w2  = (const float*)d_in[8];
  const float* dec_b2  = (const float*)d_in[9];
  const float* dec_w3  = (const float*)d_in[10];
  const float* dec_b3  = (const float*)d_in[11];
  float* out = (float*)d_out;

  float* ws = (float*)d_ws;
  float* uhat = ws;
  float* part = ws;
  unsigned short* h_hi  = (unsigned short*)(ws + 20971520);
  unsigned short* h_lo  = (unsigned short*)(ws + 25690112);
  unsigned short* wT_hi = (unsigned short*)(ws + 30408704);
  unsigned short* wT_lo = (unsigned short*)(ws + 33062912);
  float* x    = ws + 20971520;
  float* v    = ws + 22020096;
  float* bij  = ws + 22061056;
  float* crc  = ws + 22066176;
  float* abuf = ws + 22071296;
  float* sel  = ws + 23382016;
  int*   idxb = (int*)(ws + 23386112);
  float* h1   = ws + 23386368;
  unsigned short* h2b = (unsigned short*)(ws + 23517440);
  float* dummyC = ws + 23648512;

  // 1. split+transpose prim weights to bf16 hi/lo
  transpose_w_k<<<20736, 256, 0, stream>>>(prim_w, wT_hi, wT_lo);

  // 2. conv1 (fp32 GEMM), epilogue writes split-bf16 h
  gemm_k<128, 128, 8, 8, AM_CONV1, EPI_RELU_SPLIT>
      <<<dim3(2, 288, 1), 256, 0, stream>>>(data, conv1_w, conv1_b, nullptr,
                                            36864, 256, 81, 81, h_hi, h_lo);

  // 3. primary-caps conv: split-bf16 MFMA, BK=64, K-split 12 (768 blocks)
  prim_mfma_k<<<dim3(2, 32, 12), 256, 0, stream>>>(h_hi, h_lo, wT_hi, wT_lo, part);

  // 4. reduce partials + bias, squash -> x[B,512,8]
  red_squash_k<<<dim3(16, 256), 256, 0, stream>>>(part, prim_b, x);

  // 5. u_hat
  uhat_k<<<512, 256, 0, stream>>>(W_digit, x, uhat);

  // 6. routing
  zero_b_k<<<20, 256, 0, stream>>>(bij);
  route_iter_k<<<256, 256, 0, stream>>>(uhat, crc, v, abuf, 1, 1);
  bupd_k<<<20, 256, 0, stream>>>(abuf, bij);
  softmax_b_k<<<1, 512, 0, stream>>>(bij, crc);
  route_iter_k<<<256, 256, 0, stream>>>(uhat, crc, v, abuf, 0, 1);
  bupd_k<<<20, 256, 0, stream>>>(abuf, bij);
  softmax_b_k<<<1, 512, 0, stream>>>(bij, crc);
  route_iter_k<<<256, 256, 0, stream>>>(uhat, crc, v, nullptr, 0, 0);

  // 7. classes + argmax + mask
  classes_k<<<1, 256, 0, stream>>>(v, sel, idxb);

  // 8. decoder
  h1_k<<<256, 512, 0, stream>>>(sel, idxb, dec_w1, dec_b1, h1);
  gemm_k<128, 128, 8, 8, AM_PLAIN, EPI_RELU_H2B>
      <<<dim3(8, 2, 1), 256, 0, stream>>>(h1, dec_w2, dec_b2, dummyC,
                                          256, 1024, 512, 512, h2b, nullptr);
  dec3_mfma_k<<<dim3(1600, 1, 1), 256, 0, stream>>>(h2b, dec_w3, dec_b3, out);
}

// Round 3
// 1329.330 us; speedup vs baseline: 1.0047x; 1.0047x over previous
//
#include <hip/hip_runtime.h>
#include <cmath>

// ---------------------------------------------------------------------------
// CapsNet forward. Round 4:
//  - prim_mfma: staging via global_load_lds (16B direct-to-LDS DMA), source
//    pre-swizzled so LDS content is bit-identical to round 3 (rule #21).
//  - transpose_w: LDS-tiled, coalesced global read AND write, bank-swizzled.
//  - dec3/dec2/conv1/routing unchanged.
// ---------------------------------------------------------------------------

constexpr int BATCH = 256;

enum { AM_PLAIN = 0, AM_CONV1 = 1 };
enum { EPI_NONE = 0, EPI_RELU = 1, EPI_SIG = 2, EPI_RELU_SPLIT = 3, EPI_RELU_H2B = 4 };

typedef short bf16x8 __attribute__((ext_vector_type(8)));
typedef unsigned short us8 __attribute__((ext_vector_type(8)));
typedef float f32x4 __attribute__((ext_vector_type(4)));

__device__ __forceinline__ unsigned short f2b(float v) {
  unsigned int u = __float_as_uint(v);
  u += 0x7FFFu + ((u >> 16) & 1u);
  return (unsigned short)(u >> 16);
}
__device__ __forceinline__ void split_bf(float v, unsigned short& h, unsigned short& l) {
  h = f2b(v);
  l = f2b(v - __uint_as_float(((unsigned int)h) << 16));
}

// 16B global->LDS DMA. LDS dest = uniform base + lane*16 (linear);
// global src is per-lane.
__device__ __forceinline__ void gload16(unsigned short* lds, const unsigned short* g) {
  __builtin_amdgcn_global_load_lds(
      (const __attribute__((address_space(1))) unsigned int*)(g),
      (__attribute__((address_space(3))) unsigned int*)(lds), 16, 0, 0);
}

// ---------------------------------------------------------------------------
// fp32 tiled GEMM (conv1 and dec2): C[M,N] = A[M,K] * B[N,K]^T
// ---------------------------------------------------------------------------
template <int BM, int BN, int TM, int TN, int AMODE, int EPI>
__global__ __launch_bounds__(256, 2) void gemm_k(
    const float* __restrict__ A, const float* __restrict__ Bm,
    const float* __restrict__ bias, float* __restrict__ C,
    int M, int N, int K, int k_len,
    unsigned short* __restrict__ Chi, unsigned short* __restrict__ Clo) {
  static_assert(TM == 8 && TN == 8, "microtile fixed at 8x8");
  constexpr int BK = 8;
  constexpr int TX = BN / TN;

  const int tid = threadIdx.x;
  const int tx = tid % TX;
  const int ty = tid / TX;
  const int n0 = blockIdx.x * BN;
  const int m0 = blockIdx.y * BM;
  const int k_begin = blockIdx.z * k_len;
  const int k_end = k_begin + k_len;
  C += (size_t)blockIdx.z * (size_t)M * (size_t)N;

  __shared__ float As[BK][BM + 4];
  __shared__ float Bs[BK][BN + 4];

  float acc[TM][TN] = {};

  for (int kt = k_begin; kt < k_end; kt += BK) {
    __syncthreads();
    for (int base = tid * 4; base < BM * BK; base += 1024) {
      int ml = base / BK;
      int kl = base % BK;
#pragma unroll
      for (int j = 0; j < 4; j++) {
        int k = kt + kl + j;
        float v = 0.f;
        if (k < k_end) {
          if constexpr (AMODE == AM_PLAIN) {
            v = A[(size_t)(m0 + ml) * K + k];
          } else {
            int m = m0 + ml;
            int b = m / 144, p = m - b * 144;
            int py = p / 12, px = p - py * 12;
            int ky = k / 9, kx = k - ky * 9;
            v = A[b * 400 + (py + ky) * 20 + (px + kx)];
          }
        }
        As[kl + j][ml] = v;
      }
    }
    for (int base = tid * 4; base < BN * BK; base += 1024) {
      int nl = base / BK;
      int kl = base % BK;
#pragma unroll
      for (int j = 0; j < 4; j++) {
        int k = kt + kl + j;
        float v = 0.f;
        if (k < k_end) v = Bm[(size_t)(n0 + nl) * K + k];
        Bs[kl + j][nl] = v;
      }
    }
    __syncthreads();
#pragma unroll
    for (int kk = 0; kk < BK; kk++) {
      float af[TM], bf[TN];
      const float4* ap = reinterpret_cast<const float4*>(&As[kk][ty * TM]);
      reinterpret_cast<float4*>(af)[0] = ap[0];
      reinterpret_cast<float4*>(af)[1] = ap[1];
      const float4* bp = reinterpret_cast<const float4*>(&Bs[kk][tx * TN]);
      reinterpret_cast<float4*>(bf)[0] = bp[0];
      reinterpret_cast<float4*>(bf)[1] = bp[1];
#pragma unroll
      for (int i = 0; i < TM; i++)
#pragma unroll
        for (int j = 0; j < TN; j++) acc[i][j] += af[i] * bf[j];
    }
  }

#pragma unroll
  for (int i = 0; i < TM; i++) {
    int m = m0 + ty * TM + i;
#pragma unroll
    for (int j = 0; j < TN; j++) {
      int n = n0 + tx * TN + j;
      float v = acc[i][j];
      if constexpr (EPI == EPI_RELU) {
        v += bias[n];
        v = fmaxf(v, 0.f);
        C[(size_t)m * N + n] = v;
      } else if constexpr (EPI == EPI_SIG) {
        v += bias[n];
        v = 1.f / (1.f + expf(-v));
        C[(size_t)m * N + n] = v;
      } else if constexpr (EPI == EPI_RELU_SPLIT) {
        v += bias[n];
        v = fmaxf(v, 0.f);
        unsigned short hs, ls;
        split_bf(v, hs, ls);
        Chi[(size_t)m * N + n] = hs;
        Clo[(size_t)m * N + n] = ls;
      } else if constexpr (EPI == EPI_RELU_H2B) {
        v += bias[n];
        v = fmaxf(v, 0.f);
        Chi[(size_t)m * N + n] = f2b(v);
      } else {
        C[(size_t)m * N + n] = v;
      }
    }
  }
}

// ---------------------------------------------------------------------------
// prim_w [n][cin][81] -> wT_hi/lo [n][kk*256+cin] (bf16 split).
// LDS-tiled: block = (n, half-of-cin). Coalesced read of 10368 floats,
// bank-swizzled LDS scatter (idx = kk*128 + ((cin_l + 2*kk) & 127)),
// coalesced write of the transposed halves.
// ---------------------------------------------------------------------------
__global__ void transpose_w_k(const float* __restrict__ w,
                              unsigned short* __restrict__ hi,
                              unsigned short* __restrict__ lo) {
  __shared__ unsigned short shi[10368], slo[10368];
  const int n = blockIdx.x >> 1;
  const int h = blockIdx.x & 1;
  const int tid = threadIdx.x;
  const float* src = w + n * 20736 + h * 10368;   // cin in [h*128,(h+1)*128)
  for (int i = tid; i < 10368; i += 256) {
    float v = src[i];
    int cin_l = i / 81, kk = i - cin_l * 81;
    int idx = kk * 128 + ((cin_l + 2 * kk) & 127);
    unsigned short hb, lb;
    split_bf(v, hb, lb);
    shi[idx] = hb;
    slo[idx] = lb;
  }
  __syncthreads();
  unsigned short* dh = hi + n * 20736 + h * 128;
  unsigned short* dl = lo + n * 20736 + h * 128;
  for (int j = tid; j < 10368; j += 256) {
    int kk = j >> 7, cin_l = j & 127;
    int idx = (j & ~127) + ((cin_l + 2 * kk) & 127);
    dh[kk * 256 + cin_l] = shi[idx];
    dl[kk * 256 + cin_l] = slo[idx];
  }
}

// ---------------------------------------------------------------------------
// Primary-caps conv as split-bf16 MFMA implicit GEMM.
// M=4096 (b*16+q), N=256 (ch), K=20736 (kk*256+cin). K-split 12 -> partials.
// BK=64. Staging via global_load_lds: LDS dest linear (chunk g = row*8+c),
// global source pre-swizzled (logical chunk c' = c ^ (row&7)) -> LDS content
// identical to reg-staged round 3; swizzled ds_read side unchanged.
// C = Ahi*Bhi + Ahi*Blo + Alo*Bhi (drop lo*lo).
// ---------------------------------------------------------------------------
__global__ __launch_bounds__(256, 2) void prim_mfma_k(
    const unsigned short* __restrict__ Ahi, const unsigned short* __restrict__ Alo,
    const unsigned short* __restrict__ Bhi, const unsigned short* __restrict__ Blo,
    float* __restrict__ part) {
  __shared__ unsigned short Ah[128 * 64], Al[128 * 64];
  __shared__ unsigned short Bh[128 * 64], Bl[128 * 64];   // 64 KB total

  const int tid = threadIdx.x;
  const int wave = tid >> 6, lane = tid & 63;
  const int wm = (wave >> 1) * 64, wn = (wave & 1) * 64;
  const int cl = lane & 15, rq = lane >> 4;
  const int n0 = blockIdx.x * 128;
  const int m0 = blockIdx.y * 128;
  const int z = blockIdx.z;
  const int k_begin = z * 1728, k_end = k_begin + 1728;   // 27 tiles of 64

  // Per-lane staging invariants: wave handles chunks g = (wave*4+t)*64 + lane,
  // t in [0,4). row = g>>3, physical c = g&7, logical c' = c ^ (row&7).
  int s_ldso[4];     // LDS ushort offset of this instruction's 1KB span (uniform)
  int s_arow[4];     // A: b*144 + y*12 + xx  (add dy*12+dx at use)
  int s_cp8[4];      // c' * 8
  size_t s_gb[4];    // B: (n0+row)*20736 + c'*8  (add kt at use)
#pragma unroll
  for (int t = 0; t < 4; t++) {
    int g = (wave * 4 + t) * 64 + lane;
    int row = g >> 3, c = g & 7;
    int cp = c ^ (row & 7);
    s_ldso[t] = (wave * 4 + t) * 512;
    s_cp8[t] = cp * 8;
    int m = m0 + row;
    int b = m >> 4, q = m & 15;
    int y = q >> 2, xx = q & 3;
    s_arow[t] = b * 144 + y * 12 + xx;
    s_gb[t] = (size_t)(n0 + row) * 20736 + cp * 8;
  }

  f32x4 acc[4][4];
#pragma unroll
  for (int i = 0; i < 4; i++)
#pragma unroll
    for (int j = 0; j < 4; j++) acc[i][j] = f32x4{0.f, 0.f, 0.f, 0.f};

  for (int kt = k_begin; kt < k_end; kt += 64) {
    const int kk = kt >> 8;           // uniform within the tile (kt%64==0)
    const int cin0 = kt & 255;        // never crosses a cin-256 boundary
    const int dy = kk / 9, dx = kk - dy * 9;
    const int dyx = dy * 12 + dx;
    __syncthreads();                  // all waves done reading previous tile
#pragma unroll
    for (int t = 0; t < 4; t++) {
      size_t ga = ((size_t)(s_arow[t] + dyx) << 8) + cin0 + s_cp8[t];
      size_t gb = s_gb[t] + kt;
      gload16(&Ah[s_ldso[t]], Ahi + ga);
      gload16(&Al[s_ldso[t]], Alo + ga);
      gload16(&Bh[s_ldso[t]], Bhi + gb);
      gload16(&Bl[s_ldso[t]], Blo + gb);
    }
    __syncthreads();                  // drains vmcnt(0): LDS data visible

#pragma unroll
    for (int ko = 0; ko < 64; ko += 32) {
      const int cb = ko >> 3;         // chunk base: 0 or 4
      bf16x8 a_hi[4], b_hi[4], t[4];
#pragma unroll
      for (int im = 0; im < 4; im++) {
        int r = wm + im * 16 + cl;    // r&7 == cl&7
        a_hi[im] = *(const bf16x8*)&Ah[r * 64 + (((cb + rq) ^ (cl & 7)) << 3)];
      }
#pragma unroll
      for (int in = 0; in < 4; in++) {
        int r = wn + in * 16 + cl;
        b_hi[in] = *(const bf16x8*)&Bh[r * 64 + (((cb + rq) ^ (cl & 7)) << 3)];
      }
#pragma unroll
      for (int im = 0; im < 4; im++)
#pragma unroll
        for (int in = 0; in < 4; in++)
          acc[im][in] = __builtin_amdgcn_mfma_f32_16x16x32_bf16(a_hi[im], b_hi[in],
                                                                acc[im][in], 0, 0, 0);
#pragma unroll
      for (int in = 0; in < 4; in++) {
        int r = wn + in * 16 + cl;
        t[in] = *(const bf16x8*)&Bl[r * 64 + (((cb + rq) ^ (cl & 7)) << 3)];
      }
#pragma unroll
      for (int im = 0; im < 4; im++)
#pragma unroll
        for (int in = 0; in < 4; in++)
          acc[im][in] = __builtin_amdgcn_mfma_f32_16x16x32_bf16(a_hi[im], t[in],
                                                                acc[im][in], 0, 0, 0);
#pragma unroll
      for (int im = 0; im < 4; im++) {
        int r = wm + im * 16 + cl;
        t[im] = *(const bf16x8*)&Al[r * 64 + (((cb + rq) ^ (cl & 7)) << 3)];
      }
#pragma unroll
      for (int im = 0; im < 4; im++)
#pragma unroll
        for (int in = 0; in < 4; in++)
          acc[im][in] = __builtin_amdgcn_mfma_f32_16x16x32_bf16(t[im], b_hi[in],
                                                                acc[im][in], 0, 0, 0);
    }
  }

  float* Cp = part + (size_t)z * 1048576;
#pragma unroll
  for (int in = 0; in < 4; in++) {
    int n = n0 + wn + in * 16 + cl;
#pragma unroll
    for (int im = 0; im < 4; im++)
#pragma unroll
      for (int r = 0; r < 4; r++) {
        int m = m0 + wm + im * 16 + rq * 4 + r;
        Cp[(size_t)m * 256 + n] = acc[im][in][r];
      }
  }
}

// ---------------------------------------------------------------------------
// Decoder layer 3: out[256,102400] = sigmoid(h2 @ w3^T + b3).
// Tile 256(M, full) x 64(N): w3 is streamed from HBM exactly ONCE.
// A comes pre-converted to bf16 (h2b from dec2's epilogue).
// Same XOR-swizzled LDS as prim_mfma. 4 waves stacked in M.
// ---------------------------------------------------------------------------
__global__ __launch_bounds__(256, 2) void dec3_mfma_k(
    const unsigned short* __restrict__ Ab,  // h2 bf16 [256][1024]
    const float* __restrict__ Bw,           // w3 [102400][1024] fp32
    const float* __restrict__ bias,
    float* __restrict__ C) {
  constexpr int K = 1024, N = 102400;
  __shared__ unsigned short As[256 * 64];   // 32 KB
  __shared__ unsigned short Bs[64 * 64];    // 8 KB

  const int tid = threadIdx.x;
  const int wave = tid >> 6, lane = tid & 63;
  const int cl = lane & 15, rq = lane >> 4;
  const int n0 = blockIdx.x * 64;

  f32x4 acc[4][4];
#pragma unroll
  for (int i = 0; i < 4; i++)
#pragma unroll
    for (int j = 0; j < 4; j++) acc[i][j] = f32x4{0.f, 0.f, 0.f, 0.f};

  for (int kt = 0; kt < K; kt += 64) {
    __syncthreads();
#pragma unroll
    for (int j = 0; j < 8; j++) {
      int g = j * 256 + tid;          // 2048 chunks: 256 rows x 8
      int row = g >> 3, c = g & 7;
      int ld = row * 64 + ((c ^ (row & 7)) << 3);
      *(us8*)&As[ld] = *(const us8*)(Ab + (size_t)row * K + kt + c * 8);
    }
#pragma unroll
    for (int j = 0; j < 2; j++) {
      int g = j * 256 + tid;          // 512 chunks: 64 rows x 8
      int row = g >> 3, c = g & 7;
      int ld = row * 64 + ((c ^ (row & 7)) << 3);
      const float* src = Bw + (size_t)(n0 + row) * K + kt + c * 8;
      float4 v0 = *(const float4*)src;
      float4 v1 = *(const float4*)(src + 4);
      us8 h;
      h[0] = f2b(v0.x); h[1] = f2b(v0.y); h[2] = f2b(v0.z); h[3] = f2b(v0.w);
      h[4] = f2b(v1.x); h[5] = f2b(v1.y); h[6] = f2b(v1.z); h[7] = f2b(v1.w);
      *(us8*)&Bs[ld] = h;
    }
    __syncthreads();
#pragma unroll
    for (int ko = 0; ko < 64; ko += 32) {
      const int cb = ko >> 3;
      bf16x8 af[4], bq[4];
#pragma unroll
      for (int im = 0; im < 4; im++) {
        int r = wave * 64 + im * 16 + cl;   // r&7 == cl&7
        af[im] = *(const bf16x8*)&As[r * 64 + (((cb + rq) ^ (cl & 7)) << 3)];
      }
#pragma unroll
      for (int in = 0; in < 4; in++) {
        int r = in * 16 + cl;
        bq[in] = *(const bf16x8*)&Bs[r * 64 + (((cb + rq) ^ (cl & 7)) << 3)];
      }
#pragma unroll
      for (int im = 0; im < 4; im++)
#pragma unroll
        for (int in = 0; in < 4; in++)
          acc[im][in] = __builtin_amdgcn_mfma_f32_16x16x32_bf16(af[im], bq[in],
                                                                acc[im][in], 0, 0, 0);
    }
  }

#pragma unroll
  for (int in = 0; in < 4; in++) {
    int n = n0 + in * 16 + cl;
    float bn = bias[n];
#pragma unroll
    for (int im = 0; im < 4; im++)
#pragma unroll
      for (int r = 0; r < 4; r++) {
        int m = wave * 64 + im * 16 + rq * 4 + r;
        float v = acc[im][in][r] + bn;
        v = 1.f / (1.f + expf(-v));
        C[(size_t)m * N + n] = v;
      }
  }
}

// ---------------------------------------------------------------------------
// Reduce K-split partials + bias, squash over 8-dim capsule, scatter to x.
// ---------------------------------------------------------------------------
__global__ void red_squash_k(const float* __restrict__ part,
                             const float* __restrict__ prim_b,
                             float* __restrict__ x) {
  const int chg = blockIdx.x;
  const int b = blockIdx.y;
  const int tid = threadIdx.x;
  const int ch_l = tid & 15;
  const int q = tid >> 4;
  const int ch = chg * 16 + ch_l;

  float val = prim_b[ch];
#pragma unroll
  for (int z = 0; z < 12; z++) val += part[z * 1048576 + (b * 16 + q) * 256 + ch];

  __shared__ float su[16][17];
  su[q][ch_l] = val;
  __syncthreads();

  const int vec = tid >> 3;
  const int i = tid & 7;
  const int ch_l2 = vec >> 1;
  const int t = vec & 1;
  float sn = 0.f;
#pragma unroll
  for (int ii = 0; ii < 8; ii++) {
    float e = su[8 * t + ii][ch_l2];
    sn += e * e;
  }
  float factor = sn / ((1.f + sn) * sqrtf(sn));
  float e = su[8 * t + i][ch_l2];
  int chh = chg * 16 + ch_l2;
  int d8 = chh >> 5, d32 = chh & 31;
  int r = d8 * 64 + d32 * 2 + t;
  x[b * 4096 + r * 8 + i] = e * factor;
}

// u_hat[b,r,co] = sum_i W[r,co,i] * x[b,r,i].  one block per r.
__global__ void uhat_k(const float* __restrict__ W, const float* __restrict__ x,
                       float* __restrict__ uhat) {
  const int r = blockIdx.x;
  const int tid = threadIdx.x;
  __shared__ float Wl[8 * 160];
  __shared__ float xl[256 * 8];
  for (int t = tid; t < 1280; t += 256) {
    int co = t >> 3, i = t & 7;
    Wl[i * 160 + co] = W[r * 1280 + t];
  }
  for (int t = tid; t < 2048; t += 256) {
    int b = t >> 3, i = t & 7;
    xl[t] = x[b * 4096 + r * 8 + i];
  }
  __syncthreads();
  for (int item = tid; item < 256 * 160; item += 256) {
    int b = item / 160;
    int co = item - b * 160;
    float acc = 0.f;
#pragma unroll
    for (int i = 0; i < 8; i++) acc += Wl[i * 160 + co] * xl[b * 8 + i];
    uhat[b * 81920 + r * 160 + co] = acc;
  }
}

__global__ void zero_b_k(float* __restrict__ bij) {
  int id = blockIdx.x * 256 + threadIdx.x;
  if (id < 5120) bij[id] = 0.f;
}

__global__ void route_iter_k(const float* __restrict__ uhat,
                             const float* __restrict__ c_rc,
                             float* __restrict__ v_out,
                             float* __restrict__ a_buf,
                             int use_uniform, int do_update) {
  const int b = blockIdx.x;
  const int tid = threadIdx.x;
  __shared__ float c_l[5120];
  __shared__ float v_l[160];
  if (!use_uniform) {
    for (int t = tid; t < 5120; t += 256) c_l[t] = c_rc[t];
  }
  __syncthreads();
  if (tid < 160) {
    const float* up = uhat + b * 81920 + tid;
    const int cls = tid >> 4;
    float acc = 0.f;
    if (use_uniform) {
#pragma unroll 8
      for (int r = 0; r < 512; r++) acc += up[r * 160];
      acc *= (1.f / 512.f);
    } else {
#pragma unroll 8
      for (int r = 0; r < 512; r++) acc += c_l[r * 10 + cls] * up[r * 160];
    }
    float sq = acc * acc;
    float vv = sq * acc / ((1.f + sq) * sqrtf(sq));
    v_l[tid] = vv;
    v_out[b * 160 + tid] = vv;
  }
  __syncthreads();
  if (do_update) {
    for (int item = tid; item < 5120; item += 256) {
      int r = item / 10;
      int c = item - r * 10;
      const float* up2 = uhat + b * 81920 + r * 160 + c * 16;
      float a = 0.f;
#pragma unroll
      for (int o = 0; o < 16; o++) a += up2[o] * v_l[c * 16 + o];
      a_buf[b * 5120 + item] = a;
    }
  }
}

__global__ void bupd_k(const float* __restrict__ a_buf, float* __restrict__ bij) {
  int id = blockIdx.x * 256 + threadIdx.x;
  if (id >= 5120) return;
  float s = 0.f;
  for (int b = 0; b < BATCH; b++) s += a_buf[b * 5120 + id];
  bij[id] += s * (1.f / 256.f);
}

__global__ void softmax_b_k(const float* __restrict__ bij, float* __restrict__ c_rc) {
  const int tid = threadIdx.x;
  __shared__ float Ml[10], Sl[10];
  if (tid < 10) {
    float m = -1e30f;
    for (int r = 0; r < 512; r++) m = fmaxf(m, bij[r * 10 + tid]);
    float s = 0.f;
    for (int r = 0; r < 512; r++) s += expf(bij[r * 10 + tid] - m);
    Ml[tid] = m;
    Sl[tid] = s;
  }
  __syncthreads();
  if (tid < 512) {
    for (int c = 0; c < 10; c++)
      c_rc[tid * 10 + c] = expf(bij[tid * 10 + c] - Ml[c]) / Sl[c];
  }
}

__global__ void classes_k(const float* __restrict__ v, float* __restrict__ sel,
                          int* __restrict__ idxb) {
  const int b = threadIdx.x;
  float cl[10], ex[10];
  for (int c = 0; c < 10; c++) {
    float s = 0.f;
    for (int o = 0; o < 16; o++) {
      float e = v[b * 160 + c * 16 + o];
      s += e * e;
    }
    cl[c] = sqrtf(s);
  }
  __shared__ float red[256];
  __shared__ float Mc[10], Sc[10];
  for (int c = 0; c < 10; c++) {
    red[b] = cl[c];
    __syncthreads();
    for (int s = 128; s > 0; s >>= 1) {
      if (b < s) red[b] = fmaxf(red[b], red[b + s]);
      __syncthreads();
    }
    if (b == 0) Mc[c] = red[0];
    __syncthreads();
  }
  for (int c = 0; c < 10; c++) {
    ex[c] = expf(cl[c] - Mc[c]);
    red[b] = ex[c];
    __syncthreads();
    for (int s = 128; s > 0; s >>= 1) {
      if (b < s) red[b] += red[b + s];
      __syncthreads();
    }
    if (b == 0) Sc[c] = red[0];
    __syncthreads();
  }
  float best = ex[0] / Sc[0];
  int bi = 0;
  for (int c = 1; c < 10; c++) {
    float p = ex[c] / Sc[c];
    if (p > best) { best = p; bi = c; }
  }
  idxb[b] = bi;
  for (int o = 0; o < 16; o++) sel[b * 16 + o] = v[b * 160 + bi * 16 + o];
}

__global__ void h1_k(const float* __restrict__ sel, const int* __restrict__ idxb,
                     const float* __restrict__ w1, const float* __restrict__ b1,
                     float* __restrict__ h1) {
  const int b = blockIdx.x;
  const int j = threadIdx.x;
  __shared__ float ssel[16];
  __shared__ int six;
  if (j < 16) ssel[j] = sel[b * 16 + j];
  if (j == 0) six = idxb[b];
  __syncthreads();
  const float* wrow = w1 + j * 160 + six * 16;
  float acc = b1[j];
#pragma unroll
  for (int o = 0; o < 16; o++) acc += ssel[o] * wrow[o];
  h1[b * 512 + j] = fmaxf(acc, 0.f);
}

// ---------------------------------------------------------------------------
// ws layout (float offsets). Peak = 35,717,120 floats = 142.9 MB.
//   [0, 20971520)           uhat  (aliases prim partials 12 x 1048576)
//   20971520: h_hi  (ushort, 4718592 floats)   } dead after prim_mfma;
//   25690112: h_lo  (ushort, 4718592 floats)   } small buffers overlay h_hi
//   30408704: wT_hi (ushort, 2654208 floats)
//   33062912: wT_lo (ushort, 2654208 floats)   -> ends 35717120
//   overlay (post-prim, inside h_hi region):
//   x @20971520  v @22020096  bij @22061056  crc @22066176  abuf @22071296
//   sel @23382016  idx @23386112  h1 @23386368  h2b(ushort) @23517440
//   dummyC @23648512
// ---------------------------------------------------------------------------
extern "C" void kernel_launch(void* const* d_in, const int* in_sizes, int n_in,
                              void* d_out, int out_size, void* d_ws, size_t ws_size,
                              hipStream_t stream) {
  const float* data    = (const float*)d_in[0];
  const float* conv1_w = (const float*)d_in[1];
  const float* conv1_b = (const float*)d_in[2];
  const float* prim_w  = (const float*)d_in[3];
  const float* prim_b  = (const float*)d_in[4];
  const float* W_digit = (const float*)d_in[5];
  const float* dec_w1  = (const float*)d_in[6];
  const float* dec_b1  = (const float*)d_in[7];
  const float* dec_w2  = (const float*)d_in[8];
  const float* dec_b2  = (const float*)d_in[9];
  const float* dec_w3  = (const float*)d_in[10];
  const float* dec_b3  = (const float*)d_in[11];
  float* out = (float*)d_out;

  float* ws = (float*)d_ws;
  float* uhat = ws;
  float* part = ws;
  unsigned short* h_hi  = (unsigned short*)(ws + 20971520);
  unsigned short* h_lo  = (unsigned short*)(ws + 25690112);
  unsigned short* wT_hi = (unsigned short*)(ws + 30408704);
  unsigned short* wT_lo = (unsigned short*)(ws + 33062912);
  float* x    = ws + 20971520;
  float* v    = ws + 22020096;
  float* bij  = ws + 22061056;
  float* crc  = ws + 22066176;
  float* abuf = ws + 22071296;
  float* sel  = ws + 23382016;
  int*   idxb = (int*)(ws + 23386112);
  float* h1   = ws + 23386368;
  unsigned short* h2b = (unsigned short*)(ws + 23517440);
  float* dummyC = ws + 23648512;

  // 1. split+transpose prim weights to bf16 hi/lo (LDS-tiled, 2 blocks per n)
  transpose_w_k<<<512, 256, 0, stream>>>(prim_w, wT_hi, wT_lo);

  // 2. conv1 (fp32 GEMM), epilogue writes split-bf16 h
  gemm_k<128, 128, 8, 8, AM_CONV1, EPI_RELU_SPLIT>
      <<<dim3(2, 288, 1), 256, 0, stream>>>(data, conv1_w, conv1_b, nullptr,
                                            36864, 256, 81, 81, h_hi, h_lo);

  // 3. primary-caps conv: split-bf16 MFMA, BK=64, K-split 12 (768 blocks)
  prim_mfma_k<<<dim3(2, 32, 12), 256, 0, stream>>>(h_hi, h_lo, wT_hi, wT_lo, part);

  // 4. reduce partials + bias, squash -> x[B,512,8]
  red_squash_k<<<dim3(16, 256), 256, 0, stream>>>(part, prim_b, x);

  // 5. u_hat
  uhat_k<<<512, 256, 0, stream>>>(W_digit, x, uhat);

  // 6. routing
  zero_b_k<<<20, 256, 0, stream>>>(bij);
  route_iter_k<<<256, 256, 0, stream>>>(uhat, crc, v, abuf, 1, 1);
  bupd_k<<<20, 256, 0, stream>>>(abuf, bij);
  softmax_b_k<<<1, 512, 0, stream>>>(bij, crc);
  route_iter_k<<<256, 256, 0, stream>>>(uhat, crc, v, abuf, 0, 1);
  bupd_k<<<20, 256, 0, stream>>>(abuf, bij);
  softmax_b_k<<<1, 512, 0, stream>>>(bij, crc);
  route_iter_k<<<256, 256, 0, stream>>>(uhat, crc, v, nullptr, 0, 0);

  // 7. classes + argmax + mask
  classes_k<<<1, 256, 0, stream>>>(v, sel, idxb);

  // 8. decoder
  h1_k<<<256, 512, 0, stream>>>(sel, idxb, dec_w1, dec_b1, h1);
  gemm_k<128, 128, 8, 8, AM_PLAIN, EPI_RELU_H2B>
      <<<dim3(8, 2, 1), 256, 0, stream>>>(h1, dec_w2, dec_b2, dummyC,
                                          256, 1024, 512, 512, h2b, nullptr);
  dec3_mfma_k<<<dim3(1600, 1, 1), 256, 0, stream>>>(h2b, dec_w3, dec_b3, out);
}

// Round 4
// 1179.454 us; speedup vs baseline: 1.1324x; 1.1271x over previous
//
#include <hip/hip_runtime.h>
#include <cmath>

// ---------------------------------------------------------------------------
// CapsNet forward. Round 5:
//  - prim_mfma v2: 256x128 tile, 512 thr, BK=32, double-buffered 2-phase
//    prefetch (issue next-tile global_load_lds BEFORE compute, one barrier
//    per tile). Grid (2,16,8) = 256 blocks = 1/CU. Staged bytes 1.33->0.79 GB.
//  - routing chain fused: softmax inlined into route_iter, zero folded into
//    bupd(first), classes+h1 fused. 16 -> 13 launches.
// ---------------------------------------------------------------------------

constexpr int BATCH = 256;

enum { AM_PLAIN = 0, AM_CONV1 = 1 };
enum { EPI_NONE = 0, EPI_RELU = 1, EPI_SIG = 2, EPI_RELU_SPLIT = 3, EPI_RELU_H2B = 4 };

typedef short bf16x8 __attribute__((ext_vector_type(8)));
typedef unsigned short us8 __attribute__((ext_vector_type(8)));
typedef float f32x4 __attribute__((ext_vector_type(4)));

__device__ __forceinline__ unsigned short f2b(float v) {
  unsigned int u = __float_as_uint(v);
  u += 0x7FFFu + ((u >> 16) & 1u);
  return (unsigned short)(u >> 16);
}
__device__ __forceinline__ void split_bf(float v, unsigned short& h, unsigned short& l) {
  h = f2b(v);
  l = f2b(v - __uint_as_float(((unsigned int)h) << 16));
}

// 16B global->LDS DMA. LDS dest = uniform base + lane*16 (linear);
// global src is per-lane.
__device__ __forceinline__ void gload16(unsigned short* lds, const unsigned short* g) {
  __builtin_amdgcn_global_load_lds(
      (const __attribute__((address_space(1))) unsigned int*)(g),
      (__attribute__((address_space(3))) unsigned int*)(lds), 16, 0, 0);
}

// ---------------------------------------------------------------------------
// fp32 tiled GEMM (conv1 and dec2): C[M,N] = A[M,K] * B[N,K]^T
// ---------------------------------------------------------------------------
template <int BM, int BN, int TM, int TN, int AMODE, int EPI>
__global__ __launch_bounds__(256, 2) void gemm_k(
    const float* __restrict__ A, const float* __restrict__ Bm,
    const float* __restrict__ bias, float* __restrict__ C,
    int M, int N, int K, int k_len,
    unsigned short* __restrict__ Chi, unsigned short* __restrict__ Clo) {
  static_assert(TM == 8 && TN == 8, "microtile fixed at 8x8");
  constexpr int BK = 8;
  constexpr int TX = BN / TN;

  const int tid = threadIdx.x;
  const int tx = tid % TX;
  const int ty = tid / TX;
  const int n0 = blockIdx.x * BN;
  const int m0 = blockIdx.y * BM;
  const int k_begin = blockIdx.z * k_len;
  const int k_end = k_begin + k_len;
  C += (size_t)blockIdx.z * (size_t)M * (size_t)N;

  __shared__ float As[BK][BM + 4];
  __shared__ float Bs[BK][BN + 4];

  float acc[TM][TN] = {};

  for (int kt = k_begin; kt < k_end; kt += BK) {
    __syncthreads();
    for (int base = tid * 4; base < BM * BK; base += 1024) {
      int ml = base / BK;
      int kl = base % BK;
#pragma unroll
      for (int j = 0; j < 4; j++) {
        int k = kt + kl + j;
        float v = 0.f;
        if (k < k_end) {
          if constexpr (AMODE == AM_PLAIN) {
            v = A[(size_t)(m0 + ml) * K + k];
          } else {
            int m = m0 + ml;
            int b = m / 144, p = m - b * 144;
            int py = p / 12, px = p - py * 12;
            int ky = k / 9, kx = k - ky * 9;
            v = A[b * 400 + (py + ky) * 20 + (px + kx)];
          }
        }
        As[kl + j][ml] = v;
      }
    }
    for (int base = tid * 4; base < BN * BK; base += 1024) {
      int nl = base / BK;
      int kl = base % BK;
#pragma unroll
      for (int j = 0; j < 4; j++) {
        int k = kt + kl + j;
        float v = 0.f;
        if (k < k_end) v = Bm[(size_t)(n0 + nl) * K + k];
        Bs[kl + j][nl] = v;
      }
    }
    __syncthreads();
#pragma unroll
    for (int kk = 0; kk < BK; kk++) {
      float af[TM], bf[TN];
      const float4* ap = reinterpret_cast<const float4*>(&As[kk][ty * TM]);
      reinterpret_cast<float4*>(af)[0] = ap[0];
      reinterpret_cast<float4*>(af)[1] = ap[1];
      const float4* bp = reinterpret_cast<const float4*>(&Bs[kk][tx * TN]);
      reinterpret_cast<float4*>(bf)[0] = bp[0];
      reinterpret_cast<float4*>(bf)[1] = bp[1];
#pragma unroll
      for (int i = 0; i < TM; i++)
#pragma unroll
        for (int j = 0; j < TN; j++) acc[i][j] += af[i] * bf[j];
    }
  }

#pragma unroll
  for (int i = 0; i < TM; i++) {
    int m = m0 + ty * TM + i;
#pragma unroll
    for (int j = 0; j < TN; j++) {
      int n = n0 + tx * TN + j;
      float v = acc[i][j];
      if constexpr (EPI == EPI_RELU) {
        v += bias[n];
        v = fmaxf(v, 0.f);
        C[(size_t)m * N + n] = v;
      } else if constexpr (EPI == EPI_SIG) {
        v += bias[n];
        v = 1.f / (1.f + expf(-v));
        C[(size_t)m * N + n] = v;
      } else if constexpr (EPI == EPI_RELU_SPLIT) {
        v += bias[n];
        v = fmaxf(v, 0.f);
        unsigned short hs, ls;
        split_bf(v, hs, ls);
        Chi[(size_t)m * N + n] = hs;
        Clo[(size_t)m * N + n] = ls;
      } else if constexpr (EPI == EPI_RELU_H2B) {
        v += bias[n];
        v = fmaxf(v, 0.f);
        Chi[(size_t)m * N + n] = f2b(v);
      } else {
        C[(size_t)m * N + n] = v;
      }
    }
  }
}

// ---------------------------------------------------------------------------
// prim_w [n][cin][81] -> wT_hi/lo [n][kk*256+cin] (bf16 split).
// LDS-tiled: block = (n, half-of-cin).
// ---------------------------------------------------------------------------
__global__ void transpose_w_k(const float* __restrict__ w,
                              unsigned short* __restrict__ hi,
                              unsigned short* __restrict__ lo) {
  __shared__ unsigned short shi[10368], slo[10368];
  const int n = blockIdx.x >> 1;
  const int h = blockIdx.x & 1;
  const int tid = threadIdx.x;
  const float* src = w + n * 20736 + h * 10368;   // cin in [h*128,(h+1)*128)
  for (int i = tid; i < 10368; i += 256) {
    float v = src[i];
    int cin_l = i / 81, kk = i - cin_l * 81;
    int idx = kk * 128 + ((cin_l + 2 * kk) & 127);
    unsigned short hb, lb;
    split_bf(v, hb, lb);
    shi[idx] = hb;
    slo[idx] = lb;
  }
  __syncthreads();
  unsigned short* dh = hi + n * 20736 + h * 128;
  unsigned short* dl = lo + n * 20736 + h * 128;
  for (int j = tid; j < 10368; j += 256) {
    int kk = j >> 7, cin_l = j & 127;
    int idx = (j & ~127) + ((cin_l + 2 * kk) & 127);
    dh[kk * 256 + cin_l] = shi[idx];
    dl[kk * 256 + cin_l] = slo[idx];
  }
}

// ---------------------------------------------------------------------------
// Primary-caps conv, split-bf16 MFMA implicit GEMM, v2.
// M=4096, N=256, K=20736. Tile 256(M)x128(N), BK=32, K-split 8 (k_len=2592,
// 81 tiles/block, grid 2x16x8 = 256 blocks = 1/CU, 512 threads = 8 waves).
// Double-buffered LDS (96 KB) + 2-phase prefetch: STAGE(next) issued before
// COMPUTE(cur); the single __syncthreads per tile drains vmcnt after ~48
// MFMAs of cover. XOR chunk swizzle (4 chunks/row): phys c = c' ^ (row&3),
// applied via pre-swizzled global source (linear LDS dest, rule #21).
// C = Ahi*Bhi + Ahi*Blo + Alo*Bhi (drop lo*lo).
// ---------------------------------------------------------------------------
__global__ __launch_bounds__(512, 2) void prim_mfma_k(
    const unsigned short* __restrict__ Ahi, const unsigned short* __restrict__ Alo,
    const unsigned short* __restrict__ Bhi, const unsigned short* __restrict__ Blo,
    float* __restrict__ part) {
  __shared__ __align__(16) unsigned short Ah[2 * 256 * 32], Al[2 * 256 * 32];
  __shared__ __align__(16) unsigned short Bh[2 * 128 * 32], Bl[2 * 128 * 32];

  const int tid = threadIdx.x;
  const int wave = tid >> 6, lane = tid & 63;
  const int wm = (wave >> 1) * 64, wn = (wave & 1) * 64;
  const int cl = lane & 15, rq = lane >> 4;
  const int n0 = blockIdx.x * 128;
  const int m0 = blockIdx.y * 256;
  const int z = blockIdx.z;
  const int k_begin = z * 2592;        // 81 tiles of 32
  constexpr int NT = 81;

  // Staging descriptors. A: 2048 chunks/array (256 rows x 4 chunks of 16B),
  // thread handles g = tid, tid+512. B: 512 chunks/array, g = tid.
  int a_ldso[2], a_row[2], a_cp8[2];
#pragma unroll
  for (int t = 0; t < 2; t++) {
    int g = t * 512 + tid;
    int row = g >> 2, c = g & 3;
    int cp = c ^ (row & 3);
    a_ldso[t] = g * 8;
    a_cp8[t] = cp * 8;
    int m = m0 + row;
    int b = m >> 4, q = m & 15;
    int y = q >> 2, xx = q & 3;
    a_row[t] = b * 144 + y * 12 + xx;
  }
  int b_ldso;
  size_t b_base;
  {
    int row = tid >> 2, c = tid & 3;
    int cp = c ^ (row & 3);
    b_ldso = tid * 8;
    b_base = (size_t)(n0 + row) * 20736 + cp * 8;
  }

  f32x4 acc[4][4];
#pragma unroll
  for (int i = 0; i < 4; i++)
#pragma unroll
    for (int j = 0; j < 4; j++) acc[i][j] = f32x4{0.f, 0.f, 0.f, 0.f};

  auto STAGE = [&](int buf, int kt) {
    const int kk = kt >> 8;
    const int cin0 = kt & 255;
    const int dyx = (kk / 9) * 12 + (kk % 9);
    const int ab = buf * 8192, bb = buf * 4096;
#pragma unroll
    for (int t = 0; t < 2; t++) {
      size_t ga = ((size_t)(a_row[t] + dyx) << 8) + cin0 + a_cp8[t];
      gload16(&Ah[ab + a_ldso[t]], Ahi + ga);
      gload16(&Al[ab + a_ldso[t]], Alo + ga);
    }
    size_t gb = b_base + kt;
    gload16(&Bh[bb + b_ldso], Bhi + gb);
    gload16(&Bl[bb + b_ldso], Blo + gb);
  };

  auto COMPUTE = [&](int buf) {
    const int ab = buf * 8192, bb = buf * 4096;
    bf16x8 a_hi[4], b_hi[4], t[4];
#pragma unroll
    for (int im = 0; im < 4; im++) {
      int r = wm + im * 16 + cl;      // r&3 == cl&3
      a_hi[im] = *(const bf16x8*)&Ah[ab + r * 32 + ((rq ^ (r & 3)) << 3)];
    }
#pragma unroll
    for (int in = 0; in < 4; in++) {
      int r = wn + in * 16 + cl;
      b_hi[in] = *(const bf16x8*)&Bh[bb + r * 32 + ((rq ^ (r & 3)) << 3)];
    }
#pragma unroll
    for (int im = 0; im < 4; im++)
#pragma unroll
      for (int in = 0; in < 4; in++)
        acc[im][in] = __builtin_amdgcn_mfma_f32_16x16x32_bf16(a_hi[im], b_hi[in],
                                                              acc[im][in], 0, 0, 0);
#pragma unroll
    for (int in = 0; in < 4; in++) {
      int r = wn + in * 16 + cl;
      t[in] = *(const bf16x8*)&Bl[bb + r * 32 + ((rq ^ (r & 3)) << 3)];
    }
#pragma unroll
    for (int im = 0; im < 4; im++)
#pragma unroll
      for (int in = 0; in < 4; in++)
        acc[im][in] = __builtin_amdgcn_mfma_f32_16x16x32_bf16(a_hi[im], t[in],
                                                              acc[im][in], 0, 0, 0);
#pragma unroll
    for (int im = 0; im < 4; im++) {
      int r = wm + im * 16 + cl;
      t[im] = *(const bf16x8*)&Al[ab + r * 32 + ((rq ^ (r & 3)) << 3)];
    }
#pragma unroll
    for (int im = 0; im < 4; im++)
#pragma unroll
      for (int in = 0; in < 4; in++)
        acc[im][in] = __builtin_amdgcn_mfma_f32_16x16x32_bf16(t[im], b_hi[in],
                                                              acc[im][in], 0, 0, 0);
  };

  STAGE(0, k_begin);
  __syncthreads();                 // drain prologue loads
  int cur = 0;
  for (int ti = 0; ti < NT; ++ti) {
    if (ti + 1 < NT) STAGE(cur ^ 1, k_begin + (ti + 1) * 32);
    COMPUTE(cur);
    __syncthreads();               // drains prefetch (hidden under MFMAs),
    cur ^= 1;                      // and gates buffer reuse
  }

  float* Cp = part + (size_t)z * 1048576;
#pragma unroll
  for (int in = 0; in < 4; in++) {
    int n = n0 + wn + in * 16 + cl;
#pragma unroll
    for (int im = 0; im < 4; im++)
#pragma unroll
      for (int r = 0; r < 4; r++) {
        int m = m0 + wm + im * 16 + rq * 4 + r;
        Cp[(size_t)m * 256 + n] = acc[im][in][r];
      }
  }
}

// ---------------------------------------------------------------------------
// Decoder layer 3: out[256,102400] = sigmoid(h2 @ w3^T + b3).
// Tile 256(M, full) x 64(N): w3 is streamed from HBM exactly ONCE.
// ---------------------------------------------------------------------------
__global__ __launch_bounds__(256, 2) void dec3_mfma_k(
    const unsigned short* __restrict__ Ab,  // h2 bf16 [256][1024]
    const float* __restrict__ Bw,           // w3 [102400][1024] fp32
    const float* __restrict__ bias,
    float* __restrict__ C) {
  constexpr int K = 1024, N = 102400;
  __shared__ __align__(16) unsigned short As[256 * 64];   // 32 KB
  __shared__ __align__(16) unsigned short Bs[64 * 64];    // 8 KB

  const int tid = threadIdx.x;
  const int wave = tid >> 6, lane = tid & 63;
  const int cl = lane & 15, rq = lane >> 4;
  const int n0 = blockIdx.x * 64;

  f32x4 acc[4][4];
#pragma unroll
  for (int i = 0; i < 4; i++)
#pragma unroll
    for (int j = 0; j < 4; j++) acc[i][j] = f32x4{0.f, 0.f, 0.f, 0.f};

  for (int kt = 0; kt < K; kt += 64) {
    __syncthreads();
#pragma unroll
    for (int j = 0; j < 8; j++) {
      int g = j * 256 + tid;          // 2048 chunks: 256 rows x 8
      int row = g >> 3, c = g & 7;
      int ld = row * 64 + ((c ^ (row & 7)) << 3);
      *(us8*)&As[ld] = *(const us8*)(Ab + (size_t)row * K + kt + c * 8);
    }
#pragma unroll
    for (int j = 0; j < 2; j++) {
      int g = j * 256 + tid;          // 512 chunks: 64 rows x 8
      int row = g >> 3, c = g & 7;
      int ld = row * 64 + ((c ^ (row & 7)) << 3);
      const float* src = Bw + (size_t)(n0 + row) * K + kt + c * 8;
      float4 v0 = *(const float4*)src;
      float4 v1 = *(const float4*)(src + 4);
      us8 h;
      h[0] = f2b(v0.x); h[1] = f2b(v0.y); h[2] = f2b(v0.z); h[3] = f2b(v0.w);
      h[4] = f2b(v1.x); h[5] = f2b(v1.y); h[6] = f2b(v1.z); h[7] = f2b(v1.w);
      *(us8*)&Bs[ld] = h;
    }
    __syncthreads();
#pragma unroll
    for (int ko = 0; ko < 64; ko += 32) {
      const int cb = ko >> 3;
      bf16x8 af[4], bq[4];
#pragma unroll
      for (int im = 0; im < 4; im++) {
        int r = wave * 64 + im * 16 + cl;   // r&7 == cl&7
        af[im] = *(const bf16x8*)&As[r * 64 + (((cb + rq) ^ (cl & 7)) << 3)];
      }
#pragma unroll
      for (int in = 0; in < 4; in++) {
        int r = in * 16 + cl;
        bq[in] = *(const bf16x8*)&Bs[r * 64 + (((cb + rq) ^ (cl & 7)) << 3)];
      }
#pragma unroll
      for (int im = 0; im < 4; im++)
#pragma unroll
        for (int in = 0; in < 4; in++)
          acc[im][in] = __builtin_amdgcn_mfma_f32_16x16x32_bf16(af[im], bq[in],
                                                                acc[im][in], 0, 0, 0);
    }
  }

#pragma unroll
  for (int in = 0; in < 4; in++) {
    int n = n0 + in * 16 + cl;
    float bn = bias[n];
#pragma unroll
    for (int im = 0; im < 4; im++)
#pragma unroll
      for (int r = 0; r < 4; r++) {
        int m = wave * 64 + im * 16 + rq * 4 + r;
        float v = acc[im][in][r] + bn;
        v = 1.f / (1.f + expf(-v));
        C[(size_t)m * N + n] = v;
      }
  }
}

// ---------------------------------------------------------------------------
// Reduce K-split partials (z=8) + bias, squash, scatter to x.
// ---------------------------------------------------------------------------
__global__ void red_squash_k(const float* __restrict__ part,
                             const float* __restrict__ prim_b,
                             float* __restrict__ x) {
  const int chg = blockIdx.x;
  const int b = blockIdx.y;
  const int tid = threadIdx.x;
  const int ch_l = tid & 15;
  const int q = tid >> 4;
  const int ch = chg * 16 + ch_l;

  float val = prim_b[ch];
#pragma unroll
  for (int z = 0; z < 8; z++) val += part[z * 1048576 + (b * 16 + q) * 256 + ch];

  __shared__ float su[16][17];
  su[q][ch_l] = val;
  __syncthreads();

  const int vec = tid >> 3;
  const int i = tid & 7;
  const int ch_l2 = vec >> 1;
  const int t = vec & 1;
  float sn = 0.f;
#pragma unroll
  for (int ii = 0; ii < 8; ii++) {
    float e = su[8 * t + ii][ch_l2];
    sn += e * e;
  }
  float factor = sn / ((1.f + sn) * sqrtf(sn));
  float e = su[8 * t + i][ch_l2];
  int chh = chg * 16 + ch_l2;
  int d8 = chh >> 5, d32 = chh & 31;
  int r = d8 * 64 + d32 * 2 + t;
  x[b * 4096 + r * 8 + i] = e * factor;
}

// u_hat[b,r,co] = sum_i W[r,co,i] * x[b,r,i].  one block per r.
__global__ void uhat_k(const float* __restrict__ W, const float* __restrict__ x,
                       float* __restrict__ uhat) {
  const int r = blockIdx.x;
  const int tid = threadIdx.x;
  __shared__ float Wl[8 * 160];
  __shared__ float xl[256 * 8];
  for (int t = tid; t < 1280; t += 256) {
    int co = t >> 3, i = t & 7;
    Wl[i * 160 + co] = W[r * 1280 + t];
  }
  for (int t = tid; t < 2048; t += 256) {
    int b = t >> 3, i = t & 7;
    xl[t] = x[b * 4096 + r * 8 + i];
  }
  __syncthreads();
  for (int item = tid; item < 256 * 160; item += 256) {
    int b = item / 160;
    int co = item - b * 160;
    float acc = 0.f;
#pragma unroll
    for (int i = 0; i < 8; i++) acc += Wl[i * 160 + co] * xl[b * 8 + i];
    uhat[b * 81920 + r * 160 + co] = acc;
  }
}

// ---------------------------------------------------------------------------
// Routing iteration with softmax(b_ij) computed in-block from bij.
// ---------------------------------------------------------------------------
__global__ void route_iter_k(const float* __restrict__ uhat,
                             const float* __restrict__ bij,
                             float* __restrict__ v_out,
                             float* __restrict__ a_buf,
                             int use_uniform, int do_update) {
  const int b = blockIdx.x;
  const int tid = threadIdx.x;
  __shared__ float c_l[5120];
  __shared__ float v_l[160];
  __shared__ float Ml[10], Sl[10], pm[10][16];
  if (!use_uniform) {
    for (int t = tid; t < 5120; t += 256) c_l[t] = bij[t];
    __syncthreads();
    if (tid < 160) {
      int c = tid >> 4, l = tid & 15;
      float m = -1e30f;
      for (int r = l; r < 512; r += 16) m = fmaxf(m, c_l[r * 10 + c]);
      pm[c][l] = m;
    }
    __syncthreads();
    if (tid < 10) {
      float m = -1e30f;
      for (int l = 0; l < 16; l++) m = fmaxf(m, pm[tid][l]);
      Ml[tid] = m;
    }
    __syncthreads();
    if (tid < 160) {
      int c = tid >> 4, l = tid & 15;
      float s = 0.f;
      for (int r = l; r < 512; r += 16) s += expf(c_l[r * 10 + c] - Ml[c]);
      pm[c][l] = s;
    }
    __syncthreads();
    if (tid < 10) {
      float s = 0.f;
      for (int l = 0; l < 16; l++) s += pm[tid][l];
      Sl[tid] = s;
    }
    __syncthreads();
    for (int t = tid; t < 5120; t += 256) {
      int c = t % 10;
      c_l[t] = expf(c_l[t] - Ml[c]) / Sl[c];
    }
  }
  __syncthreads();
  if (tid < 160) {
    const float* up = uhat + b * 81920 + tid;
    const int cls = tid >> 4;
    float acc = 0.f;
    if (use_uniform) {
#pragma unroll 8
      for (int r = 0; r < 512; r++) acc += up[r * 160];
      acc *= (1.f / 512.f);
    } else {
#pragma unroll 8
      for (int r = 0; r < 512; r++) acc += c_l[r * 10 + cls] * up[r * 160];
    }
    float sq = acc * acc;
    float vv = sq * acc / ((1.f + sq) * sqrtf(sq));
    v_l[tid] = vv;
    v_out[b * 160 + tid] = vv;
  }
  __syncthreads();
  if (do_update) {
    for (int item = tid; item < 5120; item += 256) {
      int r = item / 10;
      int c = item - r * 10;
      const float* up2 = uhat + b * 81920 + r * 160 + c * 16;
      float a = 0.f;
#pragma unroll
      for (int o = 0; o < 16; o++) a += up2[o] * v_l[c * 16 + o];
      a_buf[b * 5120 + item] = a;
    }
  }
}

__global__ void bupd_k(const float* __restrict__ a_buf, float* __restrict__ bij,
                       int first) {
  int id = blockIdx.x * 256 + threadIdx.x;
  if (id >= 5120) return;
  float s = 0.f;
  for (int b = 0; b < BATCH; b++) s += a_buf[b * 5120 + id];
  s *= (1.f / 256.f);
  bij[id] = first ? s : bij[id] + s;
}

// ---------------------------------------------------------------------------
// classes (softmax over batch) + argmax + mask + decoder layer 1, fused.
// One block per b (512 threads). Norms recomputed redundantly per block
// (41 KFLOP, trivial) so no cross-block sync is needed.
// ---------------------------------------------------------------------------
__global__ void classes_h1_k(const float* __restrict__ v,
                             const float* __restrict__ w1,
                             const float* __restrict__ b1,
                             float* __restrict__ h1) {
  const int b = blockIdx.x;
  const int tid = threadIdx.x;
  __shared__ float ncl[2560];
  __shared__ float Mc[10], Sc[10];
  __shared__ float ssel[16];
  __shared__ int sbi;
  for (int item = tid; item < 2560; item += 512) {
    int bb = item / 10, c = item - bb * 10;
    float s = 0.f;
#pragma unroll
    for (int o = 0; o < 16; o++) {
      float e = v[bb * 160 + c * 16 + o];
      s += e * e;
    }
    ncl[item] = sqrtf(s);
  }
  __syncthreads();
  if (tid < 10) {
    float m = -1e30f;
    for (int bb = 0; bb < 256; bb++) m = fmaxf(m, ncl[bb * 10 + tid]);
    float s = 0.f;
    for (int bb = 0; bb < 256; bb++) s += expf(ncl[bb * 10 + tid] - m);
    Mc[tid] = m;
    Sc[tid] = s;
  }
  __syncthreads();
  if (tid == 0) {
    float best = -1e30f;
    int bi = 0;
    for (int c = 0; c < 10; c++) {
      float p = expf(ncl[b * 10 + c] - Mc[c]) / Sc[c];
      if (p > best) { best = p; bi = c; }
    }
    sbi = bi;
  }
  __syncthreads();
  if (tid < 16) ssel[tid] = v[b * 160 + sbi * 16 + tid];
  __syncthreads();
  const float* wrow = w1 + tid * 160 + sbi * 16;
  float acc = b1[tid];
#pragma unroll
  for (int o = 0; o < 16; o++) acc += ssel[o] * wrow[o];
  h1[b * 512 + tid] = fmaxf(acc, 0.f);
}

// ---------------------------------------------------------------------------
// ws layout (float offsets). Peak = 35,717,120 floats = 142.9 MB.
//   [0, 20971520)           uhat  (aliases prim partials 8 x 1048576)
//   20971520: h_hi  (ushort, 4718592 floats)   } dead after prim_mfma;
//   25690112: h_lo  (ushort, 4718592 floats)   } small buffers overlay h_hi
//   30408704: wT_hi (ushort, 2654208 floats)
//   33062912: wT_lo (ushort, 2654208 floats)   -> ends 35717120
//   overlay (post-prim, inside h_hi region):
//   x @20971520  v @22020096  bij @22061056  abuf @22071296
//   h1 @23386368  h2b(ushort) @23517440  dummyC @23648512
// ---------------------------------------------------------------------------
extern "C" void kernel_launch(void* const* d_in, const int* in_sizes, int n_in,
                              void* d_out, int out_size, void* d_ws, size_t ws_size,
                              hipStream_t stream) {
  const float* data    = (const float*)d_in[0];
  const float* conv1_w = (const float*)d_in[1];
  const float* conv1_b = (const float*)d_in[2];
  const float* prim_w  = (const float*)d_in[3];
  const float* prim_b  = (const float*)d_in[4];
  const float* W_digit = (const float*)d_in[5];
  const float* dec_w1  = (const float*)d_in[6];
  const float* dec_b1  = (const float*)d_in[7];
  const float* dec_w2  = (const float*)d_in[8];
  const float* dec_b2  = (const float*)d_in[9];
  const float* dec_w3  = (const float*)d_in[10];
  const float* dec_b3  = (const float*)d_in[11];
  float* out = (float*)d_out;

  float* ws = (float*)d_ws;
  float* uhat = ws;
  float* part = ws;
  unsigned short* h_hi  = (unsigned short*)(ws + 20971520);
  unsigned short* h_lo  = (unsigned short*)(ws + 25690112);
  unsigned short* wT_hi = (unsigned short*)(ws + 30408704);
  unsigned short* wT_lo = (unsigned short*)(ws + 33062912);
  float* x    = ws + 20971520;
  float* v    = ws + 22020096;
  float* bij  = ws + 22061056;
  float* abuf = ws + 22071296;
  float* h1   = ws + 23386368;
  unsigned short* h2b = (unsigned short*)(ws + 23517440);
  float* dummyC = ws + 23648512;

  // 1. split+transpose prim weights to bf16 hi/lo
  transpose_w_k<<<512, 256, 0, stream>>>(prim_w, wT_hi, wT_lo);

  // 2. conv1 (fp32 GEMM), epilogue writes split-bf16 h
  gemm_k<128, 128, 8, 8, AM_CONV1, EPI_RELU_SPLIT>
      <<<dim3(2, 288, 1), 256, 0, stream>>>(data, conv1_w, conv1_b, nullptr,
                                            36864, 256, 81, 81, h_hi, h_lo);

  // 3. primary-caps conv v2: 256x128 tile, 2-phase, K-split 8 (256 blocks)
  prim_mfma_k<<<dim3(2, 16, 8), 512, 0, stream>>>(h_hi, h_lo, wT_hi, wT_lo, part);

  // 4. reduce partials + bias, squash -> x[B,512,8]
  red_squash_k<<<dim3(16, 256), 256, 0, stream>>>(part, prim_b, x);

  // 5. u_hat
  uhat_k<<<512, 256, 0, stream>>>(W_digit, x, uhat);

  // 6. routing (softmax fused into route_iter; zero fused into bupd first=1)
  route_iter_k<<<256, 256, 0, stream>>>(uhat, bij, v, abuf, 1, 1);
  bupd_k<<<20, 256, 0, stream>>>(abuf, bij, 1);
  route_iter_k<<<256, 256, 0, stream>>>(uhat, bij, v, abuf, 0, 1);
  bupd_k<<<20, 256, 0, stream>>>(abuf, bij, 0);
  route_iter_k<<<256, 256, 0, stream>>>(uhat, bij, v, nullptr, 0, 0);

  // 7. classes + argmax + mask + decoder layer 1 (fused)
  classes_h1_k<<<256, 512, 0, stream>>>(v, dec_w1, dec_b1, h1);

  // 8. decoder layers 2,3
  gemm_k<128, 128, 8, 8, AM_PLAIN, EPI_RELU_H2B>
      <<<dim3(8, 2, 1), 256, 0, stream>>>(h1, dec_w2, dec_b2, dummyC,
                                          256, 1024, 512, 512, h2b, nullptr);
  dec3_mfma_k<<<dim3(1600, 1, 1), 256, 0, stream>>>(h2b, dec_w3, dec_b3, out);
}